// Round 18
// baseline (49.345 us; speedup 1.0000x reference)
//
#include <hip/hip_runtime.h>

#define WIN   11
#define IW    512
#define IH    512
#define OW    502         // 512 - 10
#define OH    502
#define NCH   48          // 16*3 channel-images
#define TW    54          // output columns per wave-tile
#define SWC   64          // columns computed in V: TW + 10 = one col per lane
#define SWP4  64          // float4 row stride: 8 rows x 64 x 16B = 8 KiB per wave
#define CH    8           // chunk height (output rows per chunk)
#define NCHUNK 4          // chunks per slab
#define SLABH (CH*NCHUNK) // 32 output rows per wave
#define NGX   10          // ceil(502/54)
#define NGY   16          // ceil(502/32)
#define NGZ   12          // 48 channels / 4 waves per block
#define PXL   7           // output px per lane in H (8 groups x 7 = 56 >= 54)

typedef float v2f __attribute__((ext_vector_type(2)));
typedef float v4f __attribute__((ext_vector_type(4)));

__device__ __forceinline__ float fast_rcp(float x) {
    return __builtin_amdgcn_rcpf(x);   // v_rcp_f32, ~1 ulp
}

// Per-wave slab: identical algorithm to R17 but private vb region, no barriers.
// Same-wave DS ops execute in order (LDS pipe is in-order per wave); compiler
// inserts lgkmcnt waits for read data. No cross-wave LDS sharing anywhere.
template<bool EDGE>
__device__ __forceinline__ void ssim_slab(const float* __restrict__ p1,
                                          const float* __restrict__ p2,
                                          const float (&w)[WIN],
                                          v4f (*vb)[SWP4],      // [CH][SWP4]
                                          int x0, int y0, int lane, float& acc)
{
    // ---- V mapping: one column per lane (all 64 lanes dense).
    const int c = lane;                 // 0..63
    int gx = x0 + c;
    if (EDGE) gx = min(gx, IW - 1);

    // 10-row (a,b) register history: input rows y0 .. y0+9
    v2f h[10];
#pragma unroll
    for (int j = 0; j < 10; ++j) {
        int gy = y0 + j; if (EDGE) gy = min(gy, IH - 1);
        const int gidx = gy * IW + gx;
        h[j].x = p1[gidx];
        h[j].y = p2[gidx];
    }

    // ---- H mapping: row rh, x-group gg of 7 px
    const int rh = lane & 7;            // 0..7
    const int gg = lane >> 3;           // 0..7
    const int xs = gg * PXL;            // 0,7,...,49  (float4-column units)
    const float c1 = 0.0001f;           // (0.01*1.0)^2
    const float c2 = 0.0009f;           // (0.03*1.0)^2

#pragma unroll
    for (int ci = 0; ci < NCHUNK; ++ci) {
        // ---- load this chunk's 8 new input rows (just-in-time batch)
        const int jbase = y0 + 10 + ci * CH;
        v2f n[CH];
#pragma unroll
        for (int j = 0; j < CH; ++j) {
            int gy = jbase + j; if (EDGE) gy = min(gy, IH - 1);
            const int gidx = gy * IW + gx;
            n[j].x = p1[gidx];
            n[j].y = p2[gidx];
        }

        // ---- vertical blur: 18-row window = h[0..9] ++ n[0..7]
        v2f accA[CH], accB[CH];
#pragma unroll
        for (int r = 0; r < CH; ++r) {
            accA[r] = (v2f){0.f, 0.f};
            accB[r] = (v2f){0.f, 0.f};
        }
#pragma unroll
        for (int j = 0; j < CH + 10; ++j) {
            v2f ab = (j < 10) ? h[j] : n[j - 10];
            v2f st;
            st.x = fmaf(ab.x, ab.x, ab.y * ab.y);   // a^2 + b^2
            st.y = ab.x * ab.y;                     // a*b
#pragma unroll
            for (int k = 0; k < WIN; ++k) {
                const int r = j - k;                // compile-time after unroll
                if (r >= 0 && r < CH) {
                    v2f ws; ws.x = w[k]; ws.y = w[k];
                    accA[r] = __builtin_elementwise_fma(ws, ab, accA[r]);
                    accB[r] = __builtin_elementwise_fma(ws, st, accB[r]);
                }
            }
            if (j >= 10) {                          // row j-10 complete
                v4f o4;                             // interleave planes: one b128
                o4.x = accA[j - 10].x; o4.y = accA[j - 10].y;
                o4.z = accB[j - 10].x; o4.w = accB[j - 10].y;
                vb[j - 10][c] = o4;
            }
        }
        // ---- history shift: keep last 10 window rows
#pragma unroll
        for (int j = 0; j < 10; ++j)
            h[j] = (j < 2) ? h[8 + j] : n[j - 2];

        // ---- H phase: b128 reads serve both plane-pairs for 7 px.
        // gg=7 must not read past col 63 (cols 64/65 feed only masked px).
        {
            v4f x4[17];
            const v4f* src = &vb[rh][xs];
#pragma unroll
            for (int t = 0; t < 15; ++t)
                x4[t] = src[t];
            if (gg < 7) { x4[15] = src[15]; x4[16] = src[16]; }
            else        { x4[15] = (v4f){0.f,0.f,0.f,0.f};
                          x4[16] = (v4f){0.f,0.f,0.f,0.f}; }

            const int oy = y0 + ci * CH + rh;
#pragma unroll
            for (int o = 0; o < PXL; ++o) {
                v2f sA = {0.f, 0.f}, sB = {0.f, 0.f};
#pragma unroll
                for (int k = 0; k < WIN; ++k) {
                    v4f f = x4[o + k];
                    v2f lo = __builtin_shufflevector(f, f, 0, 1);
                    v2f hi = __builtin_shufflevector(f, f, 2, 3);
                    v2f ws; ws.x = w[k]; ws.y = w[k];
                    sA = __builtin_elementwise_fma(ws, lo, sA);
                    sB = __builtin_elementwise_fma(ws, hi, sB);
                }
                const int tc = xs + o;              // tile-local column
                bool valid = (tc < TW);
                if (EDGE) valid = valid && (oy < OH) && ((x0 + tc) < OW);
                if (valid) {
                    float m1 = sA.x, m2 = sA.y;
                    float mu11 = m1 * m1, mu22 = m2 * m2, mu12 = m1 * m2;
                    float sAB = sB.x - mu11 - mu22;   // s11 + s22
                    float s12 = sB.y - mu12;
                    float num = (2.f * mu12 + c1) * (2.f * s12 + c2);
                    float den = (mu11 + mu22 + c1) * (sAB + c2);
                    acc += num * fast_rcp(den);
                }
            }
        }
        // no barrier: next chunk's V writes are same-wave, in-order after H reads
    }
}

// Grid: 10 x-tiles, 16 y-slabs, 12 z (4 channels per block).
// 256-thread blocks = 4 INDEPENDENT waves (private LDS quarters, no barriers).
// LDS = 32,768 B exactly -> 5 blocks/CU = 20 waves/CU theoretical.
__global__ __launch_bounds__(256, 2)
void ssim_fused_kernel(const float* __restrict__ img1,
                       const float* __restrict__ img2,
                       const float* __restrict__ win,
                       float* __restrict__ partial)
{
    __shared__ __align__(16) v4f vbuf[4][CH][SWP4];   // 32,768 B
    const int tid  = threadIdx.x;
    const int wid  = tid >> 6;          // wave 0..3
    const int lane = tid & 63;
    const int ch   = blockIdx.z * 4 + wid;
    const int x0 = blockIdx.x * TW;
    const int y0 = blockIdx.y * SLABH;
    const float* __restrict__ p1 = img1 + (size_t)ch * (IW * IH);
    const float* __restrict__ p2 = img2 + (size_t)ch * (IW * IH);

    float w[WIN];
#pragma unroll
    for (int k = 0; k < WIN; ++k) w[k] = win[k];

    float acc = 0.f;
    const bool edge = (blockIdx.x == gridDim.x - 1) || (blockIdx.y == gridDim.y - 1);
    if (edge) ssim_slab<true >(p1, p2, w, vbuf[wid], x0, y0, lane, acc);
    else      ssim_slab<false>(p1, p2, w, vbuf[wid], x0, y0, lane, acc);

    // ---- per-wave reduction; lane 0 of each wave writes its own partial
#pragma unroll
    for (int off = 32; off > 0; off >>= 1)
        acc += __shfl_down(acc, off, 64);
    if (lane == 0) {
        partial[(size_t)ch * (NGX * NGY) + blockIdx.y * NGX + blockIdx.x] = acc;
    }
}

__global__ __launch_bounds__(256)
void reduce_partials_kernel(const float* __restrict__ partial, int n4,
                            float* __restrict__ out, double inv_count)
{
    __shared__ double sd[256];
    const float4* p4 = reinterpret_cast<const float4*>(partial);
    double s = 0.0;
    for (int i = threadIdx.x; i < n4; i += 256) {
        float4 f = p4[i];
        s += (double)f.x + (double)f.y + (double)f.z + (double)f.w;
    }
    sd[threadIdx.x] = s;
    __syncthreads();
    for (int off = 128; off > 0; off >>= 1) {
        if (threadIdx.x < off) sd[threadIdx.x] += sd[threadIdx.x + off];
        __syncthreads();
    }
    if (threadIdx.x == 0)
        out[0] = (float)(sd[0] * inv_count);
}

extern "C" void kernel_launch(void* const* d_in, const int* in_sizes, int n_in,
                              void* d_out, int out_size, void* d_ws, size_t ws_size,
                              hipStream_t stream)
{
    const float* img1 = (const float*)d_in[0];
    const float* img2 = (const float*)d_in[1];
    const float* win  = (const float*)d_in[2];
    float* out = (float*)d_out;
    float* partial = (float*)d_ws;

    dim3 grid(NGX, NGY, NGZ);            // 10 x 16 x 12 = 1920 blocks x 4 waves
    dim3 block(256);

    ssim_fused_kernel<<<grid, block, 0, stream>>>(img1, img2, win, partial);

    const int nblocks = NGX * NGY * NCH; // 7680 wave-partials, divisible by 4
    const double inv_count = 1.0 / ((double)NCH * OW * OH);
    reduce_partials_kernel<<<1, 256, 0, stream>>>(partial, nblocks / 4, out, inv_count);
}